// Round 8
// baseline (428.875 us; speedup 1.0000x reference)
//
#include <hip/hip_runtime.h>

typedef short short8 __attribute__((ext_vector_type(8)));
typedef float f32x4 __attribute__((ext_vector_type(4)));
typedef float f32x16 __attribute__((ext_vector_type(16)));
typedef unsigned short u16x4 __attribute__((ext_vector_type(4)));

constexpr int NB = 16, CIN = 128, LIN = 2048, CO = 256;
constexpr int SL = 2041;                 // output sequence length
constexpr int MT = NB * SL;              // 32656 valid rows
constexpr int MP = 32768;                // padded rows
constexpr int XTS = 136;                 // xT row stride (elems): 16B-aligned

// ---- workspace layout (bytes, all 256-aligned) ----
constexpr size_t XT_OFF = 0;
constexpr size_t XT_SZ  = (size_t)NB*LIN*XTS*2 + 65536;  // bf16 xT [n][s][136] + OOB slack
constexpr size_t CW_OFF = XT_OFF + XT_SZ;
constexpr size_t CW_SZ  = (size_t)CO*CIN*8*2;            // conv_w bf16 [256][1024], kk=kp*128+ci
constexpr size_t WQ_OFF = CW_OFF + CW_SZ;
constexpr size_t WB_SZ  = (size_t)CO*CO*2;
constexpr size_t WK_OFF = WQ_OFF + WB_SZ;
constexpr size_t WV_OFF = WK_OFF + WB_SZ;
constexpr size_t H_OFF  = WV_OFF + WB_SZ;
constexpr size_t HB_SZ  = (size_t)MP*CO*2;               // 16 MB each
constexpr size_t Q_OFF  = H_OFF + HB_SZ;
constexpr size_t K_OFF  = Q_OFF + HB_SZ;
constexpr size_t VT_OFF = K_OFF + HB_SZ;                 // v transposed [256][16][2048]

__device__ inline unsigned short f2bf(float f) {
  union { float f; unsigned int u; } v; v.f = f;
  unsigned int r = v.u + 0x7fffu + ((v.u >> 16) & 1u);
  return (unsigned short)(r >> 16);
}

// CK-style LDS barrier: waits only lgkmcnt(0) (ds ops), does NOT drain vmcnt.
__device__ inline void sync_lds() {
  __asm__ volatile("" ::: "memory");
  __builtin_amdgcn_s_waitcnt(0xc07f);   // lgkmcnt(0)
  __builtin_amdgcn_s_barrier();
  __asm__ volatile("" ::: "memory");
}
__device__ inline void barrier_only() {
  __asm__ volatile("" ::: "memory");
  __builtin_amdgcn_s_barrier();
  __asm__ volatile("" ::: "memory");
}
__device__ inline void waitcnt_vm(int imm) {  // imm: packed simm16
  switch (imm) {
    case 0x0F70: __builtin_amdgcn_s_waitcnt(0x0F70); break;  // vmcnt(0)
    case 0x0F74: __builtin_amdgcn_s_waitcnt(0x0F74); break;  // vmcnt(4)
    default:     __builtin_amdgcn_s_waitcnt(0x0F70); break;
  }
  __asm__ volatile("" ::: "memory");
}

#if defined(__has_builtin)
#if __has_builtin(__builtin_amdgcn_global_load_lds)
#define HAVE_GLDS 1
#endif
#endif

__device__ inline void gld16(const unsigned short* g, void* l) {
#ifdef HAVE_GLDS
  __builtin_amdgcn_global_load_lds(
      (const __attribute__((address_space(1))) void*)g,
      (__attribute__((address_space(3))) void*)l, 16, 0, 0);
#else
  *(short8*)l = *(const short8*)g;
#endif
}

// ---------------- x transpose + bf16: [16][128][2048] f32 -> [16][2048][136] bf16 ----------------
__global__ void xpose_kernel(const float* __restrict__ x, unsigned short* __restrict__ xt) {
  __shared__ float tile[32][33];
  const int tx = threadIdx.x, ty = threadIdx.y;
  const int s0 = blockIdx.x * 32, c0 = blockIdx.y * 32, n = blockIdx.z;
  #pragma unroll
  for (int r = 0; r < 4; ++r)
    tile[ty * 4 + r][tx] = x[((size_t)(n * CIN + c0 + ty * 4 + r)) * LIN + s0 + tx];
  __syncthreads();
  #pragma unroll
  for (int r = 0; r < 4; ++r)
    xt[((size_t)(n * LIN + s0 + ty * 4 + r)) * XTS + c0 + tx] = f2bf(tile[tx][ty * 4 + r]);
}

// ---------------- conv weight reorder ----------------
__global__ void wconv_kernel(const float* __restrict__ w, unsigned short* __restrict__ o) {
  int idx = blockIdx.x * 256 + threadIdx.x;
  int co = idx >> 10, r = idx & 1023, kp = r >> 7, ci = r & 127;
  o[idx] = f2bf(w[co * 1024 + ci * 8 + kp]);
}

// ---------------- q/k/v weight cvt ----------------
__global__ void wqkv_kernel(const float* __restrict__ a, const float* __restrict__ b,
                            const float* __restrict__ c, unsigned short* __restrict__ oa,
                            unsigned short* __restrict__ ob, unsigned short* __restrict__ oc) {
  int z = blockIdx.x >> 6, lb = blockIdx.x & 63;
  const float* src = (z == 0) ? a : (z == 1) ? b : c;
  unsigned short* dst = (z == 0) ? oa : (z == 1) ? ob : oc;
  int i = (lb * 256 + threadIdx.x) * 4;
  float4 v = *(const float4*)(src + i);
  u16x4 r;
  r.x = f2bf(v.x); r.y = f2bf(v.y); r.z = f2bf(v.z); r.w = f2bf(v.w);
  *(u16x4*)(dst + i) = r;
}

// ---------------- conv as implicit GEMM: reg-prefetch dbuf weights ----------------
__global__ __launch_bounds__(256) void conv_gemm(
    const unsigned short* __restrict__ xt,   // [16][2048][136] bf16
    const unsigned short* __restrict__ wb,   // [256][1024] bf16 (kk = kp*128+ci)
    const float* __restrict__ bias,
    unsigned short* __restrict__ h)          // [MP][256] bf16
{
  __shared__ unsigned short sX[18432];       // 36 KB x-window
  __shared__ unsigned short sB[2][4096];     // 2 x 8 KB weight chunk, chunk-swizzled
  const int tid = threadIdx.x;
  const int w = tid >> 6, lane = tid & 63, quad = lane >> 4, l16 = lane & 15;
  const int n  = blockIdx.y;
  const int s0 = blockIdx.x * 128;
  const int d0 = blockIdx.z * 128;

  {
    const unsigned short* xbase = xt + ((size_t)n * LIN + s0) * XTS;
    #pragma unroll
    for (int i = 0; i < 9; ++i) {
      int u = i * 256 + tid;
      gld16(xbase + u * 8, ((char*)sX) + u * 16);
    }
  }

  const int brow0 = tid >> 2, bkgs = tid & 3;
  short8 breg[2];
  #pragma unroll
  for (int i2 = 0; i2 < 2; ++i2) {
    int row = i2 * 64 + brow0;
    int kg = bkgs ^ ((row >> 1) & 3);
    breg[i2] = *(const short8*)(wb + (size_t)(d0 + row) * 1024 + kg * 8);
  }
  #pragma unroll
  for (int i2 = 0; i2 < 2; ++i2)
    *(short8*)(&sB[0][(i2 * 256 + tid) * 8]) = breg[i2];
  __syncthreads();                          // full drain once (X DMA + sB[0])

  f32x4 acc[2][8];
  #pragma unroll
  for (int i = 0; i < 2; ++i)
    #pragma unroll
    for (int j = 0; j < 8; ++j) acc[i][j] = (f32x4){0.f, 0.f, 0.f, 0.f};

  for (int kc = 0; kc < 32; ++kc) {
    const int kcn = (kc < 31) ? kc + 1 : kc;
    const int kpn = kcn >> 2, ci0n = (kcn & 3) * 32;
    #pragma unroll
    for (int i2 = 0; i2 < 2; ++i2) {
      int row = i2 * 64 + brow0;
      int kg = bkgs ^ ((row >> 1) & 3);
      breg[i2] = *(const short8*)(wb + (size_t)(d0 + row) * 1024 + kpn * 128 + ci0n + kg * 8);
    }

    const int kp = kc >> 2, ci0 = (kc & 3) * 32;
    const unsigned short* sBc = sB[kc & 1];
    short8 bfr[8];
    #pragma unroll
    for (int j = 0; j < 8; ++j) {
      int r = j * 16 + l16;
      bfr[j] = *(const short8*)(sBc + r * 32 + (quad ^ ((r >> 1) & 3)) * 8);
    }
    #pragma unroll
    for (int i = 0; i < 2; ++i) {
      int srow = w * 32 + i * 16 + l16;
      short8 afr = *(const short8*)(sX + (srow + kp) * XTS + ci0 + quad * 8);
      #pragma unroll
      for (int j = 0; j < 8; ++j)
        acc[i][j] = __builtin_amdgcn_mfma_f32_16x16x32_bf16(afr, bfr[j], acc[i][j], 0, 0, 0);
    }

    #pragma unroll
    for (int i2 = 0; i2 < 2; ++i2)
      *(short8*)(&sB[(kc + 1) & 1][(i2 * 256 + tid) * 8]) = breg[i2];
    sync_lds();
  }

  #pragma unroll
  for (int i = 0; i < 2; ++i)
    #pragma unroll
    for (int j = 0; j < 8; ++j) {
      int col = d0 + j * 16 + l16;
      float bv = bias[col];
      #pragma unroll
      for (int jj = 0; jj < 4; ++jj) {
        int s = s0 + w * 32 + i * 16 + quad * 4 + jj;
        if (s < SL) {
          float val = fmaxf(acc[i][j][jj] + bv, 0.f);
          h[(size_t)(n * SL + s) * CO + col] = f2bf(val);
        }
      }
    }
}

// ---------------- q/k/v linear GEMMs: reg-prefetch dbuf A and B ----------------
__global__ __launch_bounds__(256) void lin_gemm(
    const unsigned short* __restrict__ A,    // h [MP][256]
    const unsigned short* __restrict__ Bq, const unsigned short* __restrict__ Bk,
    const unsigned short* __restrict__ Bv,
    const float* __restrict__ biq, const float* __restrict__ bik,
    const float* __restrict__ biv,
    unsigned short* __restrict__ qb, unsigned short* __restrict__ kb,
    unsigned short* __restrict__ vtb)
{
  __shared__ unsigned short sA[2][4096];
  __shared__ unsigned short sB[2][4096];
  const int tid = threadIdx.x;
  const int w = tid >> 6, lane = tid & 63, quad = lane >> 4, l16 = lane & 15;
  const int m0 = blockIdx.x * 128, d0 = blockIdx.y * 128, z = blockIdx.z;
  const unsigned short* B = (z == 0) ? Bq : (z == 1) ? Bk : Bv;
  const float* bias        = (z == 0) ? biq : (z == 1) ? bik : biv;

  const int brow0 = tid >> 2, bkgs = tid & 3;
  short8 areg[2], breg[2];
  #pragma unroll
  for (int i2 = 0; i2 < 2; ++i2) {
    int row = i2 * 64 + brow0;
    int kg = bkgs ^ ((row >> 1) & 3);
    areg[i2] = *(const short8*)(A + (size_t)(m0 + row) * CO + kg * 8);
    breg[i2] = *(const short8*)(B + (size_t)(d0 + row) * CO + kg * 8);
  }
  #pragma unroll
  for (int i2 = 0; i2 < 2; ++i2) {
    *(short8*)(&sA[0][(i2 * 256 + tid) * 8]) = areg[i2];
    *(short8*)(&sB[0][(i2 * 256 + tid) * 8]) = breg[i2];
  }
  sync_lds();

  f32x4 acc[2][8];
  #pragma unroll
  for (int i = 0; i < 2; ++i)
    #pragma unroll
    for (int j = 0; j < 8; ++j) acc[i][j] = (f32x4){0.f, 0.f, 0.f, 0.f};

  for (int kc = 0; kc < 8; ++kc) {
    const int kcn = (kc < 7) ? kc + 1 : kc;
    #pragma unroll
    for (int i2 = 0; i2 < 2; ++i2) {
      int row = i2 * 64 + brow0;
      int kg = bkgs ^ ((row >> 1) & 3);
      areg[i2] = *(const short8*)(A + (size_t)(m0 + row) * CO + kcn * 32 + kg * 8);
      breg[i2] = *(const short8*)(B + (size_t)(d0 + row) * CO + kcn * 32 + kg * 8);
    }

    const unsigned short* sAc = sA[kc & 1];
    const unsigned short* sBc = sB[kc & 1];
    short8 afr[2], bfr[8];
    #pragma unroll
    for (int i = 0; i < 2; ++i) {
      int r = w * 32 + i * 16 + l16;
      afr[i] = *(const short8*)(sAc + r * 32 + (quad ^ ((r >> 1) & 3)) * 8);
    }
    #pragma unroll
    for (int j = 0; j < 8; ++j) {
      int r = j * 16 + l16;
      bfr[j] = *(const short8*)(sBc + r * 32 + (quad ^ ((r >> 1) & 3)) * 8);
    }
    #pragma unroll
    for (int i = 0; i < 2; ++i)
      #pragma unroll
      for (int j = 0; j < 8; ++j)
        acc[i][j] = __builtin_amdgcn_mfma_f32_16x16x32_bf16(afr[i], bfr[j], acc[i][j], 0, 0, 0);

    #pragma unroll
    for (int i2 = 0; i2 < 2; ++i2) {
      *(short8*)(&sA[(kc + 1) & 1][(i2 * 256 + tid) * 8]) = areg[i2];
      *(short8*)(&sB[(kc + 1) & 1][(i2 * 256 + tid) * 8]) = breg[i2];
    }
    sync_lds();
  }

  #pragma unroll
  for (int i = 0; i < 2; ++i)
    #pragma unroll
    for (int j = 0; j < 8; ++j) {
      int col = d0 + j * 16 + l16;
      float bv = bias[col];
      #pragma unroll
      for (int jj = 0; jj < 4; ++jj) {
        int m = m0 + w * 32 + i * 16 + quad * 4 + jj;
        float val = acc[i][j][jj] + bv;
        if (z < 2) {
          ((z == 0) ? qb : kb)[(size_t)m * CO + col] = f2bf(val);
        } else if (m < MT) {
          int nn = m / SL, ss = m - nn * SL;
          vtb[(size_t)col * MP + nn * 2048 + ss] = f2bf(val);
        }
      }
    }
}

// ---------------- fused sigmoid attention: phase-interleaved DMA, 80 KB LDS, 2 blocks/CU ------
// grid 256, 512 threads = 8 waves (sr=w&3 s-range, tr=w>>2 t/d-half), s-tile 128, t-tile 64.
// Single sK/sV/sP; V(i) DMA overlaps QK(i), K(i+1) DMA overlaps PV(i). Fine vmcnt(4) waits;
// no full drains in the loop. LDS exactly 80 KB -> 2 blocks/CU = 16 waves/CU.
__global__ __launch_bounds__(512, 4) void attn_kernel(
    const unsigned short* __restrict__ qb,   // [MP][256]
    const unsigned short* __restrict__ kb,   // [MP][256]
    const unsigned short* __restrict__ vtb,  // [256][16][2048]
    float* __restrict__ out)                 // [16][256][2041]
{
  __shared__ unsigned short sK[16384];       // 32 KB: [32 c-chunks][64 t][16B]
  __shared__ unsigned short sV[16384];       // 32 KB: [8 t-chunks][256 d][16B]
  __shared__ unsigned short sP[8192];        // 16 KB: [8 t-chunks][128 s][16B]
  const int tid = threadIdx.x;
  const int w = tid >> 6, lane = tid & 63;
  const int half = lane >> 5, l32 = lane & 31;
  const int bidx = blockIdx.x;
  const int n = (bidx & 7) + ((bidx >> 7) << 3);   // XCD-pinned: 2 n's per XCD
  const int s0 = ((bidx >> 3) & 15) * 128;
  const int sr = w & 3, tr = w >> 2;

  const unsigned short* kbN = kb + (size_t)(n * SL) * CO;
  const unsigned short* vbN = vtb + (size_t)n * 2048;

  // K: u = i*512+tid -> t = u&63, g = u>>6 ; V: d = u&255, g = u>>8. 4 insts each.
#define STAGE_K(tk)                                                              \
  { _Pragma("unroll")                                                            \
    for (int i = 0; i < 4; ++i) {                                                \
      int u = i * 512 + tid;                                                     \
      gld16(kbN + (size_t)((tk) + (u & 63)) * CO + (u >> 6) * 8,                 \
            ((char*)sK) + u * 16);                                               \
    } }
#define STAGE_V(tk)                                                              \
  { _Pragma("unroll")                                                            \
    for (int i = 0; i < 4; ++i) {                                                \
      int u = i * 512 + tid;                                                     \
      gld16(vbN + (size_t)(u & 255) * MP + (tk) + (u >> 8) * 8,                  \
            ((char*)sV) + u * 16);                                               \
    } }

  STAGE_K(0)

  // Q frags (B-operand): element (s = s0+sr*32+l32, c = kk*16+half*8+j)
  short8 qf[16];
  {
    const unsigned short* qp = qb + (size_t)(n * SL + s0 + sr * 32 + l32) * CO + half * 8;
    #pragma unroll
    for (int kk = 0; kk < 16; ++kk) qf[kk] = *(const short8*)(qp + kk * 16);
  }

  STAGE_V(0)

  f32x16 o[4];
  #pragma unroll
  for (int di = 0; di < 4; ++di)
    #pragma unroll
    for (int r = 0; r < 16; ++r) o[di][r] = 0.f;

  for (int it = 0; it < 32; ++it) {
    // B4: K(it) (+qf on it=0) ready; V(it) still in flight (4 newest)
    waitcnt_vm(0x0F74);
    barrier_only();

    // QK^T as mfma(kf, qf): C col = s (lane), rows = t
    const int tl = tr * 32 + l32;
    f32x16 sacc;
    #pragma unroll
    for (int r = 0; r < 16; ++r) sacc[r] = 0.f;
    #pragma unroll
    for (int kk = 0; kk < 16; ++kk) {
      short8 kf = *(const short8*)(sK + (((kk * 2 + half) << 6) + tl) * 8);
      sacc = __builtin_amdgcn_mfma_f32_32x32x16_bf16(kf, qf[kk], sacc, 0, 0, 0);
    }

    // sigmoid + packed b64 P-write
    const int t0 = it * 64;
    #pragma unroll
    for (int q2 = 0; q2 < 4; ++q2) {
      u16x4 pk;
      #pragma unroll
      for (int e = 0; e < 4; ++e) {
        int tg = t0 + tr * 32 + 8 * q2 + 4 * half + e;
        float p = __builtin_amdgcn_rcpf(1.f + __expf(-sacc[q2 * 4 + e] * 0.0625f));
        pk[e] = (tg < SL) ? f2bf(p) : (unsigned short)0;
      }
      *(u16x4*)(sP + ((tr * 4 + q2) * 128 + sr * 32 + l32) * 8 + 4 * half) = pk;
    }
    sync_lds();                              // B1: sP visible + all sK reads done

    if (it < 31) STAGE_K(t0 + 64)            // overwrites sK (safe after B1)

    // B2: V(it) ready (older than K(it+1)'s 4)
    waitcnt_vm(it < 31 ? 0x0F74 : 0x0F70);
    barrier_only();

    // P·V as mfma(vf, pa): C col = s, rows = d
    #pragma unroll
    for (int kt = 0; kt < 4; ++kt) {
      int g = kt * 2 + half;
      short8 pa = *(const short8*)(sP + ((g << 7) + sr * 32 + l32) * 8);
      #pragma unroll
      for (int di = 0; di < 4; ++di) {
        int d = tr * 128 + di * 32 + l32;
        short8 vf = *(const short8*)(sV + ((g << 8) + d) * 8);
        o[di] = __builtin_amdgcn_mfma_f32_32x32x16_bf16(vf, pa, o[di], 0, 0, 0);
      }
    }
    sync_lds();                              // B3: all sV/sP reads done

    if (it < 31) STAGE_V(t0 + 64)            // overwrites sV (safe after B3)
  }

  // store: C col = s (coalesced 32-lane runs), rows = d
  const int s = s0 + sr * 32 + l32;
  if (s < SL) {
    float* op = out + (size_t)n * CO * SL + s;
    #pragma unroll
    for (int di = 0; di < 4; ++di)
      #pragma unroll
      for (int r = 0; r < 16; ++r) {
        int d = tr * 128 + di * 32 + (r & 3) + 8 * (r >> 2) + 4 * half;
        __builtin_nontemporal_store(o[di][r], op + (size_t)d * SL);
      }
  }
#undef STAGE_K
#undef STAGE_V
}

extern "C" void kernel_launch(void* const* d_in, const int* in_sizes, int n_in,
                              void* d_out, int out_size, void* d_ws, size_t ws_size,
                              hipStream_t stream) {
  const float* x      = (const float*)d_in[0];
  const float* conv_w = (const float*)d_in[1];
  const float* conv_b = (const float*)d_in[2];
  const float* wq     = (const float*)d_in[3];
  const float* bq     = (const float*)d_in[4];
  const float* wk     = (const float*)d_in[5];
  const float* bk     = (const float*)d_in[6];
  const float* wv     = (const float*)d_in[7];
  const float* bv     = (const float*)d_in[8];

  char* ws = (char*)d_ws;
  unsigned short* xt  = (unsigned short*)(ws + XT_OFF);
  unsigned short* cw  = (unsigned short*)(ws + CW_OFF);
  unsigned short* wqb = (unsigned short*)(ws + WQ_OFF);
  unsigned short* wkb = (unsigned short*)(ws + WK_OFF);
  unsigned short* wvb = (unsigned short*)(ws + WV_OFF);
  unsigned short* hb  = (unsigned short*)(ws + H_OFF);
  unsigned short* qb  = (unsigned short*)(ws + Q_OFF);
  unsigned short* kb  = (unsigned short*)(ws + K_OFF);
  unsigned short* vtb = (unsigned short*)(ws + VT_OFF);

  hipLaunchKernelGGL(xpose_kernel, dim3(64, 4, 16), dim3(32, 8), 0, stream, x, xt);
  hipLaunchKernelGGL(wconv_kernel, dim3(1024), dim3(256), 0, stream, conv_w, cw);
  hipLaunchKernelGGL(wqkv_kernel,  dim3(192), dim3(256), 0, stream,
                     wq, wk, wv, wqb, wkb, wvb);
  hipLaunchKernelGGL(conv_gemm, dim3(16, 16, 2), dim3(256), 0, stream, xt, cw, conv_b, hb);
  hipLaunchKernelGGL(lin_gemm,  dim3(256, 2, 3), dim3(256), 0, stream,
                     hb, wqb, wkb, wvb, bq, bk, bv, qb, kb, vtb);
  hipLaunchKernelGGL(attn_kernel, dim3(256), dim3(512), 0, stream,
                     qb, kb, vtb, (float*)d_out);
}

// Round 9
// 246.912 us; speedup vs baseline: 1.7370x; 1.7370x over previous
//
#include <hip/hip_runtime.h>

typedef short short8 __attribute__((ext_vector_type(8)));
typedef float f32x4 __attribute__((ext_vector_type(4)));
typedef float f32x16 __attribute__((ext_vector_type(16)));
typedef unsigned short u16x4 __attribute__((ext_vector_type(4)));

constexpr int NB = 16, CIN = 128, LIN = 2048, CO = 256;
constexpr int SL = 2041;                 // output sequence length
constexpr int MT = NB * SL;              // 32656 valid rows
constexpr int MP = 32768;                // padded rows
constexpr int XTS = 136;                 // xT row stride (elems): 16B-aligned

// ---- workspace layout (bytes, all 256-aligned) ----
constexpr size_t XT_OFF = 0;
constexpr size_t XT_SZ  = (size_t)NB*LIN*XTS*2 + 65536;  // bf16 xT [n][s][136] + OOB slack
constexpr size_t CW_OFF = XT_OFF + XT_SZ;
constexpr size_t CW_SZ  = (size_t)CO*CIN*8*2;            // conv_w bf16 [256][1024], kk=kp*128+ci
constexpr size_t WQ_OFF = CW_OFF + CW_SZ;
constexpr size_t WB_SZ  = (size_t)CO*CO*2;
constexpr size_t WK_OFF = WQ_OFF + WB_SZ;
constexpr size_t WV_OFF = WK_OFF + WB_SZ;
constexpr size_t H_OFF  = WV_OFF + WB_SZ;
constexpr size_t HB_SZ  = (size_t)MP*CO*2;               // 16 MB each
constexpr size_t Q_OFF  = H_OFF + HB_SZ;
constexpr size_t K_OFF  = Q_OFF + HB_SZ;
constexpr size_t VT_OFF = K_OFF + HB_SZ;                 // v transposed [256][16][2048]

__device__ inline unsigned short f2bf(float f) {
  union { float f; unsigned int u; } v; v.f = f;
  unsigned int r = v.u + 0x7fffu + ((v.u >> 16) & 1u);
  return (unsigned short)(r >> 16);
}

// CK-style LDS barrier: waits only lgkmcnt(0) (ds ops), does NOT drain vmcnt.
__device__ inline void sync_lds() {
  __asm__ volatile("" ::: "memory");
  __builtin_amdgcn_s_waitcnt(0xc07f);   // lgkmcnt(0)
  __builtin_amdgcn_s_barrier();
  __asm__ volatile("" ::: "memory");
}
__device__ inline void barrier_only() {
  __asm__ volatile("" ::: "memory");
  __builtin_amdgcn_s_barrier();
  __asm__ volatile("" ::: "memory");
}

#if defined(__has_builtin)
#if __has_builtin(__builtin_amdgcn_global_load_lds)
#define HAVE_GLDS 1
#endif
#endif

__device__ inline void gld16(const unsigned short* g, void* l) {
#ifdef HAVE_GLDS
  __builtin_amdgcn_global_load_lds(
      (const __attribute__((address_space(1))) void*)g,
      (__attribute__((address_space(3))) void*)l, 16, 0, 0);
#else
  *(short8*)l = *(const short8*)g;
#endif
}

// ---------------- x transpose + bf16: [16][128][2048] f32 -> [16][2048][136] bf16 ----------------
__global__ void xpose_kernel(const float* __restrict__ x, unsigned short* __restrict__ xt) {
  __shared__ float tile[32][33];
  const int tx = threadIdx.x, ty = threadIdx.y;
  const int s0 = blockIdx.x * 32, c0 = blockIdx.y * 32, n = blockIdx.z;
  #pragma unroll
  for (int r = 0; r < 4; ++r)
    tile[ty * 4 + r][tx] = x[((size_t)(n * CIN + c0 + ty * 4 + r)) * LIN + s0 + tx];
  __syncthreads();
  #pragma unroll
  for (int r = 0; r < 4; ++r)
    xt[((size_t)(n * LIN + s0 + ty * 4 + r)) * XTS + c0 + tx] = f2bf(tile[tx][ty * 4 + r]);
}

// ---------------- conv weight reorder ----------------
__global__ void wconv_kernel(const float* __restrict__ w, unsigned short* __restrict__ o) {
  int idx = blockIdx.x * 256 + threadIdx.x;
  int co = idx >> 10, r = idx & 1023, kp = r >> 7, ci = r & 127;
  o[idx] = f2bf(w[co * 1024 + ci * 8 + kp]);
}

// ---------------- q/k/v weight cvt ----------------
__global__ void wqkv_kernel(const float* __restrict__ a, const float* __restrict__ b,
                            const float* __restrict__ c, unsigned short* __restrict__ oa,
                            unsigned short* __restrict__ ob, unsigned short* __restrict__ oc) {
  int z = blockIdx.x >> 6, lb = blockIdx.x & 63;
  const float* src = (z == 0) ? a : (z == 1) ? b : c;
  unsigned short* dst = (z == 0) ? oa : (z == 1) ? ob : oc;
  int i = (lb * 256 + threadIdx.x) * 4;
  float4 v = *(const float4*)(src + i);
  u16x4 r;
  r.x = f2bf(v.x); r.y = f2bf(v.y); r.z = f2bf(v.z); r.w = f2bf(v.w);
  *(u16x4*)(dst + i) = r;
}

// ---------------- conv as implicit GEMM: reg-prefetch dbuf weights ----------------
__global__ __launch_bounds__(256) void conv_gemm(
    const unsigned short* __restrict__ xt,   // [16][2048][136] bf16
    const unsigned short* __restrict__ wb,   // [256][1024] bf16 (kk = kp*128+ci)
    const float* __restrict__ bias,
    unsigned short* __restrict__ h)          // [MP][256] bf16
{
  __shared__ unsigned short sX[18432];       // 36 KB x-window
  __shared__ unsigned short sB[2][4096];     // 2 x 8 KB weight chunk, chunk-swizzled
  const int tid = threadIdx.x;
  const int w = tid >> 6, lane = tid & 63, quad = lane >> 4, l16 = lane & 15;
  const int n  = blockIdx.y;
  const int s0 = blockIdx.x * 128;
  const int d0 = blockIdx.z * 128;

  {
    const unsigned short* xbase = xt + ((size_t)n * LIN + s0) * XTS;
    #pragma unroll
    for (int i = 0; i < 9; ++i) {
      int u = i * 256 + tid;
      gld16(xbase + u * 8, ((char*)sX) + u * 16);
    }
  }

  const int brow0 = tid >> 2, bkgs = tid & 3;
  short8 breg[2];
  #pragma unroll
  for (int i2 = 0; i2 < 2; ++i2) {
    int row = i2 * 64 + brow0;
    int kg = bkgs ^ ((row >> 1) & 3);
    breg[i2] = *(const short8*)(wb + (size_t)(d0 + row) * 1024 + kg * 8);
  }
  #pragma unroll
  for (int i2 = 0; i2 < 2; ++i2)
    *(short8*)(&sB[0][(i2 * 256 + tid) * 8]) = breg[i2];
  __syncthreads();                          // full drain once (X DMA + sB[0])

  f32x4 acc[2][8];
  #pragma unroll
  for (int i = 0; i < 2; ++i)
    #pragma unroll
    for (int j = 0; j < 8; ++j) acc[i][j] = (f32x4){0.f, 0.f, 0.f, 0.f};

  for (int kc = 0; kc < 32; ++kc) {
    const int kcn = (kc < 31) ? kc + 1 : kc;
    const int kpn = kcn >> 2, ci0n = (kcn & 3) * 32;
    #pragma unroll
    for (int i2 = 0; i2 < 2; ++i2) {
      int row = i2 * 64 + brow0;
      int kg = bkgs ^ ((row >> 1) & 3);
      breg[i2] = *(const short8*)(wb + (size_t)(d0 + row) * 1024 + kpn * 128 + ci0n + kg * 8);
    }

    const int kp = kc >> 2, ci0 = (kc & 3) * 32;
    const unsigned short* sBc = sB[kc & 1];
    short8 bfr[8];
    #pragma unroll
    for (int j = 0; j < 8; ++j) {
      int r = j * 16 + l16;
      bfr[j] = *(const short8*)(sBc + r * 32 + (quad ^ ((r >> 1) & 3)) * 8);
    }
    #pragma unroll
    for (int i = 0; i < 2; ++i) {
      int srow = w * 32 + i * 16 + l16;
      short8 afr = *(const short8*)(sX + (srow + kp) * XTS + ci0 + quad * 8);
      #pragma unroll
      for (int j = 0; j < 8; ++j)
        acc[i][j] = __builtin_amdgcn_mfma_f32_16x16x32_bf16(afr, bfr[j], acc[i][j], 0, 0, 0);
    }

    #pragma unroll
    for (int i2 = 0; i2 < 2; ++i2)
      *(short8*)(&sB[(kc + 1) & 1][(i2 * 256 + tid) * 8]) = breg[i2];
    sync_lds();
  }

  #pragma unroll
  for (int i = 0; i < 2; ++i)
    #pragma unroll
    for (int j = 0; j < 8; ++j) {
      int col = d0 + j * 16 + l16;
      float bv = bias[col];
      #pragma unroll
      for (int jj = 0; jj < 4; ++jj) {
        int s = s0 + w * 32 + i * 16 + quad * 4 + jj;
        if (s < SL) {
          float val = fmaxf(acc[i][j][jj] + bv, 0.f);
          h[(size_t)(n * SL + s) * CO + col] = f2bf(val);
        }
      }
    }
}

// ---------------- q/k/v linear GEMMs: reg-prefetch dbuf A and B ----------------
__global__ __launch_bounds__(256) void lin_gemm(
    const unsigned short* __restrict__ A,    // h [MP][256]
    const unsigned short* __restrict__ Bq, const unsigned short* __restrict__ Bk,
    const unsigned short* __restrict__ Bv,
    const float* __restrict__ biq, const float* __restrict__ bik,
    const float* __restrict__ biv,
    unsigned short* __restrict__ qb, unsigned short* __restrict__ kb,
    unsigned short* __restrict__ vtb)
{
  __shared__ unsigned short sA[2][4096];
  __shared__ unsigned short sB[2][4096];
  const int tid = threadIdx.x;
  const int w = tid >> 6, lane = tid & 63, quad = lane >> 4, l16 = lane & 15;
  const int m0 = blockIdx.x * 128, d0 = blockIdx.y * 128, z = blockIdx.z;
  const unsigned short* B = (z == 0) ? Bq : (z == 1) ? Bk : Bv;
  const float* bias        = (z == 0) ? biq : (z == 1) ? bik : biv;

  const int brow0 = tid >> 2, bkgs = tid & 3;
  short8 areg[2], breg[2];
  #pragma unroll
  for (int i2 = 0; i2 < 2; ++i2) {
    int row = i2 * 64 + brow0;
    int kg = bkgs ^ ((row >> 1) & 3);
    areg[i2] = *(const short8*)(A + (size_t)(m0 + row) * CO + kg * 8);
    breg[i2] = *(const short8*)(B + (size_t)(d0 + row) * CO + kg * 8);
  }
  #pragma unroll
  for (int i2 = 0; i2 < 2; ++i2) {
    *(short8*)(&sA[0][(i2 * 256 + tid) * 8]) = areg[i2];
    *(short8*)(&sB[0][(i2 * 256 + tid) * 8]) = breg[i2];
  }
  sync_lds();

  f32x4 acc[2][8];
  #pragma unroll
  for (int i = 0; i < 2; ++i)
    #pragma unroll
    for (int j = 0; j < 8; ++j) acc[i][j] = (f32x4){0.f, 0.f, 0.f, 0.f};

  for (int kc = 0; kc < 8; ++kc) {
    const int kcn = (kc < 7) ? kc + 1 : kc;
    #pragma unroll
    for (int i2 = 0; i2 < 2; ++i2) {
      int row = i2 * 64 + brow0;
      int kg = bkgs ^ ((row >> 1) & 3);
      areg[i2] = *(const short8*)(A + (size_t)(m0 + row) * CO + kcn * 32 + kg * 8);
      breg[i2] = *(const short8*)(B + (size_t)(d0 + row) * CO + kcn * 32 + kg * 8);
    }

    const unsigned short* sAc = sA[kc & 1];
    const unsigned short* sBc = sB[kc & 1];
    short8 afr[2], bfr[8];
    #pragma unroll
    for (int i = 0; i < 2; ++i) {
      int r = w * 32 + i * 16 + l16;
      afr[i] = *(const short8*)(sAc + r * 32 + (quad ^ ((r >> 1) & 3)) * 8);
    }
    #pragma unroll
    for (int j = 0; j < 8; ++j) {
      int r = j * 16 + l16;
      bfr[j] = *(const short8*)(sBc + r * 32 + (quad ^ ((r >> 1) & 3)) * 8);
    }
    #pragma unroll
    for (int i = 0; i < 2; ++i)
      #pragma unroll
      for (int j = 0; j < 8; ++j)
        acc[i][j] = __builtin_amdgcn_mfma_f32_16x16x32_bf16(afr[i], bfr[j], acc[i][j], 0, 0, 0);

    #pragma unroll
    for (int i2 = 0; i2 < 2; ++i2) {
      *(short8*)(&sA[(kc + 1) & 1][(i2 * 256 + tid) * 8]) = areg[i2];
      *(short8*)(&sB[(kc + 1) & 1][(i2 * 256 + tid) * 8]) = breg[i2];
    }
    sync_lds();
  }

  #pragma unroll
  for (int i = 0; i < 2; ++i)
    #pragma unroll
    for (int j = 0; j < 8; ++j) {
      int col = d0 + j * 16 + l16;
      float bv = bias[col];
      #pragma unroll
      for (int jj = 0; jj < 4; ++jj) {
        int m = m0 + w * 32 + i * 16 + quad * 4 + jj;
        float val = acc[i][j][jj] + bv;
        if (z < 2) {
          ((z == 0) ? qb : kb)[(size_t)m * CO + col] = f2bf(val);
        } else if (m < MT) {
          int nn = m / SL, ss = m - nn * SL;
          vtb[(size_t)col * MP + nn * 2048 + ss] = f2bf(val);
        }
      }
    }
}

// ---------------- fused sigmoid attention: r7 dbuf pipeline + COALESCED staging ---------------
// grid 256, 512 threads = 8 waves (sr=w&3 s-range, tr=w>>2 t/d-half), s-tile 128, t-tile 64.
// LDS (144 KB): sK[2]: [64 t][32 slots x 16B], slot s holds global c-chunk s^(t&31);
//               sV[2]: [256 d][8 slots x 16B], slot s holds global t-chunk s^(d&7);
//               sP:    [8 t-chunks][128 s][16B].
// Row-major + XOR-slot => every gld16 wave-inst touches 16 cache lines (coalesced), unlike
// the r7/r8 chunk-major layout (64 lines/inst, 4x VMEM request amplification).
// Per iter: issue next-tile DMA (8 insts/thread), s_waitcnt vmcnt(8) = wait PREV tile only.
__global__ __launch_bounds__(512, 2) void attn_kernel(
    const unsigned short* __restrict__ qb,   // [MP][256]
    const unsigned short* __restrict__ kb,   // [MP][256]
    const unsigned short* __restrict__ vtb,  // [256][16][2048]
    float* __restrict__ out)                 // [16][256][2041]
{
  __shared__ unsigned short sK[2][16384];    // 2 x 32 KB
  __shared__ unsigned short sV[2][16384];    // 2 x 32 KB
  __shared__ unsigned short sP[8192];        // 16 KB
  const int tid = threadIdx.x;
  const int w = tid >> 6, lane = tid & 63;
  const int half = lane >> 5, l32 = lane & 31;
  const int bidx = blockIdx.x;
  const int n = (bidx & 7) + ((bidx >> 7) << 3);   // XCD-pinned: 2 n's per XCD
  const int s0 = ((bidx >> 3) & 15) * 128;
  const int sr = w & 3, tr = w >> 2;         // tr doubles as d-half in PV

  const unsigned short* kbN = kb + (size_t)(n * SL) * CO;
  const unsigned short* vbN = vtb + (size_t)n * 2048;

  // K: u = i*512+tid -> t = u>>5, slot = u&31; cell holds global chunk slot^(t&31).
  // V: u -> d = u>>3, slot = u&7; cell holds global t-chunk slot^(d&7).
  // Wave-inst global footprint: K = 2 rows x 512 B, V = 8 rows x 128 B -> 16 lines each.
#define STAGE_TILE(buf, tk)                                                      \
  {                                                                              \
    _Pragma("unroll")                                                            \
    for (int i = 0; i < 4; ++i) {                                                \
      int u = i * 512 + tid;                                                     \
      int t = u >> 5, sl = u & 31;                                               \
      gld16(kbN + (size_t)((tk) + t) * CO + ((sl ^ (t & 31)) << 3),              \
            ((char*)sK[buf]) + u * 16);                                          \
    }                                                                            \
    _Pragma("unroll")                                                            \
    for (int i = 0; i < 4; ++i) {                                                \
      int u = i * 512 + tid;                                                     \
      int d = u >> 3, sl = u & 7;                                                \
      gld16(vbN + (size_t)d * MP + (tk) + ((sl ^ (d & 7)) << 3),                 \
            ((char*)sV[buf]) + u * 16);                                          \
    }                                                                            \
  }

  STAGE_TILE(0, 0)

  // Q frags (B-operand): element (s = s0+sr*32+l32, c = kk*16+half*8+j)
  short8 qf[16];
  {
    const unsigned short* qp = qb + (size_t)(n * SL + s0 + sr * 32 + l32) * CO + half * 8;
    #pragma unroll
    for (int kk = 0; kk < 16; ++kk) qf[kk] = *(const short8*)(qp + kk * 16);
  }

  __builtin_amdgcn_s_waitcnt(0x0F70);        // vmcnt(0): tile0 + Q resident
  barrier_only();

  f32x16 o[4];
  #pragma unroll
  for (int di = 0; di < 4; ++di)
    #pragma unroll
    for (int r = 0; r < 16; ++r) o[di][r] = 0.f;

  for (int it = 0; it < 32; ++it) {
    const int cur = it & 1;
    if (it < 31) {
      STAGE_TILE(cur ^ 1, (it + 1) * 64)
      __builtin_amdgcn_s_waitcnt(0x0F78);    // vmcnt(8): wait only tile-it's 8 DMA insts
    } else {
      __builtin_amdgcn_s_waitcnt(0x0F70);    // last tile
    }
    barrier_only();                          // all waves' tile-it DMA complete

    // QK^T as mfma(kf, qf): A rows = t, B cols = s  =>  C col = s (lane), rows = t
    const unsigned short* sKc = sK[cur];
    const int tl = tr * 32 + l32;
    f32x16 sacc;
    #pragma unroll
    for (int r = 0; r < 16; ++r) sacc[r] = 0.f;
    #pragma unroll
    for (int kk = 0; kk < 16; ++kk) {
      short8 kf = *(const short8*)(sKc + tl * 256 + (((kk * 2 + half) ^ (tl & 31)) << 3));
      sacc = __builtin_amdgcn_mfma_f32_32x32x16_bf16(kf, qf[kk], sacc, 0, 0, 0);
    }

    // sigmoid + packed b64 P-write: quad q2 -> 4 consecutive t at fixed s
    const int t0 = it * 64;
    #pragma unroll
    for (int q2 = 0; q2 < 4; ++q2) {
      u16x4 pk;
      #pragma unroll
      for (int e = 0; e < 4; ++e) {
        int tg = t0 + tr * 32 + 8 * q2 + 4 * half + e;
        float p = __builtin_amdgcn_rcpf(1.f + __expf(-sacc[q2 * 4 + e] * 0.0625f));
        pk[e] = (tg < SL) ? f2bf(p) : (unsigned short)0;
      }
      *(u16x4*)(sP + ((tr * 4 + q2) * 128 + sr * 32 + l32) * 8 + 4 * half) = pk;
    }
    sync_lds();                              // sP complete; sK[cur] reads done

    // P·V as mfma(vf, pa): A rows = d, B cols = s  =>  C col = s, rows = d
    const unsigned short* sVc = sV[cur];
    #pragma unroll
    for (int kt = 0; kt < 4; ++kt) {
      int g = kt * 2 + half;
      short8 pa = *(const short8*)(sP + ((g << 7) + sr * 32 + l32) * 8);
      #pragma unroll
      for (int di = 0; di < 4; ++di) {
        int d = tr * 128 + di * 32 + l32;
        short8 vf = *(const short8*)(sVc + d * 64 + ((g ^ (d & 7)) << 3));
        o[di] = __builtin_amdgcn_mfma_f32_32x32x16_bf16(vf, pa, o[di], 0, 0, 0);
      }
    }
    sync_lds();                              // sV[cur]/sP reads done -> safe to overwrite
  }

  // store: C col = s = s0+sr*32+l32 (coalesced 32-lane runs), rows = d
  const int s = s0 + sr * 32 + l32;
  if (s < SL) {
    float* op = out + (size_t)n * CO * SL + s;
    #pragma unroll
    for (int di = 0; di < 4; ++di)
      #pragma unroll
      for (int r = 0; r < 16; ++r) {
        int d = tr * 128 + di * 32 + (r & 3) + 8 * (r >> 2) + 4 * half;
        __builtin_nontemporal_store(o[di][r], op + (size_t)d * SL);
      }
  }
#undef STAGE_TILE
}

extern "C" void kernel_launch(void* const* d_in, const int* in_sizes, int n_in,
                              void* d_out, int out_size, void* d_ws, size_t ws_size,
                              hipStream_t stream) {
  const float* x      = (const float*)d_in[0];
  const float* conv_w = (const float*)d_in[1];
  const float* conv_b = (const float*)d_in[2];
  const float* wq     = (const float*)d_in[3];
  const float* bq     = (const float*)d_in[4];
  const float* wk     = (const float*)d_in[5];
  const float* bk     = (const float*)d_in[6];
  const float* wv     = (const float*)d_in[7];
  const float* bv     = (const float*)d_in[8];

  char* ws = (char*)d_ws;
  unsigned short* xt  = (unsigned short*)(ws + XT_OFF);
  unsigned short* cw  = (unsigned short*)(ws + CW_OFF);
  unsigned short* wqb = (unsigned short*)(ws + WQ_OFF);
  unsigned short* wkb = (unsigned short*)(ws + WK_OFF);
  unsigned short* wvb = (unsigned short*)(ws + WV_OFF);
  unsigned short* hb  = (unsigned short*)(ws + H_OFF);
  unsigned short* qb  = (unsigned short*)(ws + Q_OFF);
  unsigned short* kb  = (unsigned short*)(ws + K_OFF);
  unsigned short* vtb = (unsigned short*)(ws + VT_OFF);

  hipLaunchKernelGGL(xpose_kernel, dim3(64, 4, 16), dim3(32, 8), 0, stream, x, xt);
  hipLaunchKernelGGL(wconv_kernel, dim3(1024), dim3(256), 0, stream, conv_w, cw);
  hipLaunchKernelGGL(wqkv_kernel,  dim3(192), dim3(256), 0, stream,
                     wq, wk, wv, wqb, wkb, wvb);
  hipLaunchKernelGGL(conv_gemm, dim3(16, 16, 2), dim3(256), 0, stream, xt, cw, conv_b, hb);
  hipLaunchKernelGGL(lin_gemm,  dim3(256, 2, 3), dim3(256), 0, stream,
                     hb, wqb, wkb, wvb, bq, bk, bv, qb, kb, vtb);
  hipLaunchKernelGGL(attn_kernel, dim3(256), dim3(512), 0, stream,
                     qb, kb, vtb, (float*)d_out);
}